// Round 1
// baseline (348.064 us; speedup 1.0000x reference)
//
#include <hip/hip_runtime.h>

// GRAPHEDX forward — fp32, multi-kernel v1 (correctness + structure round).
// Sizes (all compile-time): B=48, NQ=20, NC=16, NMAX=20, D=32, EH=64,
// NPAIR=C(20,2)=190, NTOT=1728, NE=6720, PROP=5, ITERS=20, 1/TEMP=100.

constexpr int kB    = 48;
constexpr int kNQ   = 20;
constexpr int kNC   = 16;
constexpr int kNM   = 20;    // NMAX
constexpr int kD    = 32;
constexpr int kEH   = 64;
constexpr int kNP   = 190;   // triu pairs
constexpr int kNTOT = 1728;
constexpr int kNE   = 6720;
constexpr int kIters = 20;
constexpr float kInvT = 100.0f;

// triu_indices(20,1) row-major: p -> (s,d), s<d
__device__ __forceinline__ void pair_sd(int p, int& s, int& d) {
    int row = 0, rem = p;
    #pragma unroll
    for (int r = 0; r < 19; ++r) {
        int len = 19 - r;
        if (rem < len) { row = r; break; }
        rem -= len;
    }
    s = row; d = row + 1 + rem;
}

// ---------------- encoders ----------------
__global__ void k_enc_node(const float* __restrict__ nf, const float* __restrict__ w,
                           const float* __restrict__ b, float* __restrict__ h) {
    int idx = blockIdx.x * 256 + threadIdx.x;          // NTOT*32 = 55296
    int n = idx >> 5, c = idx & 31;
    float acc = b[c];
    const float* row = nf + n * 16;
    #pragma unroll
    for (int k = 0; k < 16; ++k) acc += row[k] * w[k * 32 + c];
    h[idx] = acc;
}

__global__ void k_enc_edge(const float* __restrict__ ef, const float* __restrict__ w,
                           const float* __restrict__ b, float* __restrict__ e) {
    int idx = blockIdx.x * 256 + threadIdx.x;          // NE*16 = 107520
    int n = idx >> 4, c = idx & 15;
    float acc = b[c];
    const float* row = ef + n * 8;
    #pragma unroll
    for (int k = 0; k < 8; ++k) acc += row[k] * w[k * 16 + c];
    e[idx] = acc;
}

// ---------------- message + scatter ----------------
__global__ void k_msg(const float* __restrict__ h, const float* __restrict__ ee,
                      const int* __restrict__ fidx, const int* __restrict__ tidx,
                      const float* __restrict__ w1, const float* __restrict__ b1,
                      const float* __restrict__ w2, const float* __restrict__ b2,
                      float* __restrict__ agg) {
    __shared__ float xs[4][80];
    __shared__ float hs[4][64];
    int w = threadIdx.x >> 6, lane = threadIdx.x & 63;
    int e = blockIdx.x * 4 + w;                        // 6720 edges, 1680 blocks
    int from = fidx[e], to = tidx[e];
    if (lane < 32) xs[w][lane] = h[from * kD + lane];
    else           xs[w][lane] = h[to * kD + (lane - 32)];
    if (lane < 16) xs[w][64 + lane] = ee[e * 16 + lane];
    __syncthreads();
    float acc = b1[lane];
    #pragma unroll 8
    for (int k = 0; k < 80; ++k) acc += xs[w][k] * w1[k * 64 + lane];
    hs[w][lane] = fmaxf(acc, 0.f);
    __syncthreads();
    float o = b2[lane];
    #pragma unroll 8
    for (int k = 0; k < 64; ++k) o += hs[w][k] * w2[k * 64 + lane];
    atomicAdd(&agg[to * 64 + lane], o);
}

// ---------------- node update (also re-zeroes agg for next round) ----------------
__global__ void k_upd(float* __restrict__ h, float* __restrict__ agg,
                      const float* __restrict__ w1, const float* __restrict__ b1,
                      const float* __restrict__ w2, const float* __restrict__ b2) {
    __shared__ float xs[4][96];
    __shared__ float hs[4][64];
    int w = threadIdx.x >> 6, lane = threadIdx.x & 63;
    int n = blockIdx.x * 4 + w;                        // 1728 nodes, 432 blocks
    xs[w][lane] = agg[n * 64 + lane];
    agg[n * 64 + lane] = 0.f;                          // zero for next prop round
    if (lane < 32) xs[w][64 + lane] = h[n * kD + lane];
    __syncthreads();
    float acc = b1[lane];
    #pragma unroll 8
    for (int k = 0; k < 96; ++k) acc += xs[w][k] * w1[k * 64 + lane];
    hs[w][lane] = fmaxf(acc, 0.f);
    __syncthreads();
    if (lane < 32) {
        float o = b2[lane];
        #pragma unroll 8
        for (int k = 0; k < 64; ++k) o += hs[w][k] * w2[k * 32 + lane];
        h[n * kD + lane] += o;
    }
}

// ---------------- build Hq/Hc (padded) + sink MLP t-vectors ----------------
__global__ void k_sink_t(const float* __restrict__ h,
                         const float* __restrict__ w1, const float* __restrict__ b1,
                         const float* __restrict__ w2, const float* __restrict__ b2,
                         float* __restrict__ Hq, float* __restrict__ Hc,
                         float* __restrict__ tq, float* __restrict__ tc) {
    __shared__ float xs[4][32];
    __shared__ float hs[4][20];
    int w = threadIdx.x >> 6, lane = threadIdx.x & 63;
    int id = blockIdx.x * 4 + w;                       // 2*48*20 = 1920, 480 blocks
    int side = id / (kB * kNM);
    int rem  = id % (kB * kNM);
    int b = rem / kNM, i = rem % kNM;
    if (lane < 32) {
        float v;
        if (side == 0) v = h[(b * 36 + i) * kD + lane];
        else           v = (i < kNC) ? h[(b * 36 + kNQ + i) * kD + lane] : 0.f;
        (side ? Hc : Hq)[(b * kNM + i) * kD + lane] = v;
        xs[w][lane] = v;
    }
    __syncthreads();
    if (lane < kNM) {
        float acc = b1[lane];
        #pragma unroll
        for (int k = 0; k < kD; ++k) acc += xs[w][k] * w1[k * kNM + lane];
        hs[w][lane] = fmaxf(acc, 0.f);
    }
    __syncthreads();
    if (lane < kNM) {
        float o = b2[lane];
        #pragma unroll
        for (int k = 0; k < kNM; ++k) o += hs[w][k] * w2[k * kNM + lane];
        (side ? tc : tq)[(b * kNM + i) * kNM + lane] = o;
    }
}

// ---------------- cost + Sinkhorn + node_align ----------------
__global__ void k_sinkhorn(const float* __restrict__ tq, const float* __restrict__ tc,
                           const float* __restrict__ Hq,
                           float* __restrict__ P, float* __restrict__ out) {
    __shared__ float la[400], A[400], C[400];
    int b = blockIdx.x, t = threadIdx.x;               // 48 blocks x 64 threads
    for (int idx = t; idx < 400; idx += 64) { A[idx] = tq[b * 400 + idx]; C[idx] = tc[b * 400 + idx]; }
    __syncthreads();
    for (int pr = t; pr < 400; pr += 64) {
        int i = pr / 20, j = pr % 20;
        float c = 0.f;
        #pragma unroll
        for (int k = 0; k < 20; ++k) c += fabsf(A[i * 20 + k] - C[j * 20 + k]);
        la[pr] = -c * kInvT;
    }
    __syncthreads();
    for (int it = 0; it < kIters; ++it) {
        if (t < 20) {                                  // row LSE (over j)
            float m = -3.0e38f;
            #pragma unroll
            for (int j = 0; j < 20; ++j) m = fmaxf(m, la[t * 20 + j]);
            float s = 0.f;
            #pragma unroll
            for (int j = 0; j < 20; ++j) s += expf(la[t * 20 + j] - m);
            float l = m + logf(s);
            #pragma unroll
            for (int j = 0; j < 20; ++j) la[t * 20 + j] -= l;
        }
        __syncthreads();
        if (t < 20) {                                  // col LSE (over i)
            float m = -3.0e38f;
            #pragma unroll
            for (int i = 0; i < 20; ++i) m = fmaxf(m, la[i * 20 + t]);
            float s = 0.f;
            #pragma unroll
            for (int i = 0; i < 20; ++i) s += expf(la[i * 20 + t] - m);
            float l = m + logf(s);
            #pragma unroll
            for (int i = 0; i < 20; ++i) la[i * 20 + t] -= l;
        }
        __syncthreads();
    }
    for (int idx = t; idx < 400; idx += 64) P[b * 400 + idx] = expf(la[idx]);
    // node_align: NXOR nonzero only for j>=16 where Hc==0 -> ncost = L1(Hq row)
    float part = 0.f;
    if (t < 20) {
        float pr = 0.f;
        #pragma unroll
        for (int j = 16; j < 20; ++j) pr += expf(la[t * 20 + j]);
        float l1 = 0.f;
        #pragma unroll
        for (int k = 0; k < 32; ++k) l1 += fabsf(Hq[(b * 20 + t) * 32 + k]);
        part = pr * l1;
    }
    #pragma unroll
    for (int off = 32; off; off >>= 1) part += __shfl_down(part, off, 64);
    if (t == 0) atomicAdd(&out[b], part);
}

// ---------------- edge embeddings (f + bk fused, both sides) ----------------
__global__ void k_edge_emb(const float* __restrict__ Hq, const float* __restrict__ Hc,
                           const float* __restrict__ qadj, const float* __restrict__ cadj,
                           const float* __restrict__ w1, const float* __restrict__ b1,
                           const float* __restrict__ w2, const float* __restrict__ b2,
                           float* __restrict__ Eq, float* __restrict__ Ec) {
    __shared__ float xs[4][66];
    __shared__ float hs[4][64];
    int w = threadIdx.x >> 6, lane = threadIdx.x & 63;
    int id = blockIdx.x * 4 + w;                       // 2*48*190 = 18240, 4560 blocks
    int side = id / (kB * kNP);
    int rem  = id % (kB * kNP);
    int b = rem / kNP, p = rem % kNP;
    int sp, dp; pair_sd(p, sp, dp);
    const float* H   = side ? Hc : Hq;
    const float* adj = side ? cadj : qadj;
    if (lane < 32) xs[w][lane] = H[(b * kNM + sp) * kD + lane];
    else           xs[w][lane] = H[(b * kNM + dp) * kD + (lane - 32)];
    if (lane == 0) xs[w][64] = adj[b * 400 + sp * 20 + dp];
    __syncthreads();
    float af = b1[lane], ab = af;
    #pragma unroll 8
    for (int k = 0; k < 64; ++k) {
        float wk = w1[k * 64 + lane];
        af += xs[w][k] * wk;
        ab += xs[w][(k + 32) & 63] * wk;
    }
    {
        float wk = w1[64 * 64 + lane];
        float ev = xs[w][64];
        af += ev * wk; ab += ev * wk;
    }
    hs[w][lane] = fmaxf(af, 0.f) + fmaxf(ab, 0.f);
    __syncthreads();
    float o = 2.f * b2[lane];
    #pragma unroll 8
    for (int k = 0; k < 64; ++k) o += hs[w][k] * w2[k * 64 + lane];
    (side ? Ec : Eq)[(b * kNP + p) * 64 + lane] = o;
}

// ---------------- edge_align: sum_pq pxor * eT * L1(Eq_p, Ec_q) ----------------
constexpr int kNBPB = 8;   // blocks per batch element
__global__ void k_final(const float* __restrict__ P, const float* __restrict__ Eq,
                        const float* __restrict__ Ec, const float* __restrict__ qadj,
                        const float* __restrict__ cadj, float* __restrict__ out) {
    __shared__ float EcS[kNP * 65];    // +1 pad: lanes=q read spreads banks
    __shared__ float Ps[400];
    __shared__ float acs[kNP];
    __shared__ short sqt[kNP], dqt[kNP];
    int b = blockIdx.x / kNBPB, chunk = blockIdx.x % kNBPB;
    int t = threadIdx.x, w = t >> 6, lane = t & 63;
    for (int idx = t; idx < 400; idx += 256) Ps[idx] = P[b * 400 + idx];
    for (int q = t; q < kNP; q += 256) {
        int s, d; pair_sd(q, s, d);
        sqt[q] = (short)s; dqt[q] = (short)d;
        acs[q] = cadj[b * 400 + s * 20 + d];
    }
    for (int idx = t; idx < kNP * 64; idx += 256) {
        int q = idx >> 6, d = idx & 63;
        EcS[q * 65 + d] = Ec[b * kNP * 64 + idx];
    }
    __syncthreads();

    float partial = 0.f;
    for (int p = chunk * 4 + w; p < kNP; p += kNBPB * 4) {   // 32 waves per b
        int sp, dp; pair_sd(p, sp, dp);
        float aq = qadj[b * 400 + sp * 20 + dp];
        bool aqb = aq > 0.5f;
        const float* eq = Eq + (b * kNP + p) * 64;
        #pragma unroll
        for (int g = 0; g < 3; ++g) {
            int myq = g * 64 + lane;
            bool valid = myq < kNP;
            int qi = valid ? myq : 0;
            float wq = 0.f;
            if (valid) {
                int sq = sqt[qi], dq = dqt[qi];
                float eT = Ps[sp * 20 + sq] * Ps[dp * 20 + dq]
                         + Ps[sp * 20 + dq] * Ps[dp * 20 + sq];
                float acv = acs[qi];
                float gate = aqb ? (1.f - acv) : acv;       // aq XOR ac
                wq = gate * eT;
            }
            float ce = 0.f;
            #pragma unroll
            for (int d = 0; d < 64; d += 4) {
                float4 e4 = *(const float4*)(eq + d);
                ce += fabsf(e4.x - EcS[qi * 65 + d]);
                ce += fabsf(e4.y - EcS[qi * 65 + d + 1]);
                ce += fabsf(e4.z - EcS[qi * 65 + d + 2]);
                ce += fabsf(e4.w - EcS[qi * 65 + d + 3]);
            }
            partial += wq * ce;
        }
    }
    #pragma unroll
    for (int off = 32; off; off >>= 1) partial += __shfl_down(partial, off, 64);
    if (lane == 0) atomicAdd(&out[b], partial);
}

extern "C" void kernel_launch(void* const* d_in, const int* in_sizes, int n_in,
                              void* d_out, int out_size, void* d_ws, size_t ws_size,
                              hipStream_t stream) {
    auto f = [&](int i) { return (const float*)d_in[i]; };
    const float* nf   = f(0);
    const float* ef   = f(1);
    const float* qadj = f(2);
    const float* cadj = f(3);
    const int* from_idx = (const int*)d_in[24];
    const int* to_idx   = (const int*)d_in[25];
    float* out = (float*)d_out;

    float* ws  = (float*)d_ws;
    float* h   = ws;                       // 55296
    float* ee  = h   + 55296;              // 107520
    float* agg = ee  + 107520;             // 110592
    float* Hq  = agg + 110592;             // 30720
    float* Hc  = Hq  + 30720;              // 30720
    float* tq  = Hc  + 30720;              // 19200
    float* tc  = tq  + 19200;              // 19200
    float* P   = tc  + 19200;              // 19200
    float* Eq  = P   + 19200;              // 583680
    float* Ec  = Eq  + 583680;             // 583680

    hipMemsetAsync(out, 0, kB * sizeof(float), stream);
    hipMemsetAsync(agg, 0, kNTOT * kEH * sizeof(float), stream);

    k_enc_node<<<216, 256, 0, stream>>>(nf, f(4), f(5), h);
    k_enc_edge<<<420, 256, 0, stream>>>(ef, f(6), f(7), ee);
    for (int it = 0; it < 5; ++it) {
        k_msg<<<1680, 256, 0, stream>>>(h, ee, from_idx, to_idx,
                                        f(8), f(9), f(10), f(11), agg);
        k_upd<<<432, 256, 0, stream>>>(h, agg, f(12), f(13), f(14), f(15));
    }
    k_sink_t<<<480, 256, 0, stream>>>(h, f(16), f(17), f(18), f(19), Hq, Hc, tq, tc);
    k_sinkhorn<<<48, 64, 0, stream>>>(tq, tc, Hq, P, out);
    k_edge_emb<<<4560, 256, 0, stream>>>(Hq, Hc, qadj, cadj,
                                         f(20), f(21), f(22), f(23), Eq, Ec);
    k_final<<<kB * kNBPB, 256, 0, stream>>>(P, Eq, Ec, qadj, cadj, out);
}

// Round 2
// 229.232 us; speedup vs baseline: 1.5184x; 1.5184x over previous
//
#include <hip/hip_runtime.h>

// GRAPHEDX forward — fp32 v2: k_final restructured (lanes = feature dim,
// Ec tile in registers, wq via shuffle broadcast, no LDS tile).

constexpr int kB    = 48;
constexpr int kNQ   = 20;
constexpr int kNC   = 16;
constexpr int kNM   = 20;    // NMAX
constexpr int kD    = 32;
constexpr int kEH   = 64;
constexpr int kNP   = 190;   // triu pairs
constexpr int kNTOT = 1728;
constexpr int kIters = 20;
constexpr float kInvT = 100.0f;

// triu_indices(20,1) row-major: p -> (s,d), s<d
__device__ __forceinline__ void pair_sd(int p, int& s, int& d) {
    int row = 0, rem = p;
    #pragma unroll
    for (int r = 0; r < 19; ++r) {
        int len = 19 - r;
        if (rem < len) { row = r; break; }
        rem -= len;
    }
    s = row; d = row + 1 + rem;
}

// ---------------- encoders ----------------
__global__ void k_enc_node(const float* __restrict__ nf, const float* __restrict__ w,
                           const float* __restrict__ b, float* __restrict__ h) {
    int idx = blockIdx.x * 256 + threadIdx.x;          // NTOT*32 = 55296
    int n = idx >> 5, c = idx & 31;
    float acc = b[c];
    const float* row = nf + n * 16;
    #pragma unroll
    for (int k = 0; k < 16; ++k) acc += row[k] * w[k * 32 + c];
    h[idx] = acc;
}

__global__ void k_enc_edge(const float* __restrict__ ef, const float* __restrict__ w,
                           const float* __restrict__ b, float* __restrict__ e) {
    int idx = blockIdx.x * 256 + threadIdx.x;          // NE*16 = 107520
    int n = idx >> 4, c = idx & 15;
    float acc = b[c];
    const float* row = ef + n * 8;
    #pragma unroll
    for (int k = 0; k < 8; ++k) acc += row[k] * w[k * 16 + c];
    e[idx] = acc;
}

// ---------------- message + scatter ----------------
__global__ void k_msg(const float* __restrict__ h, const float* __restrict__ ee,
                      const int* __restrict__ fidx, const int* __restrict__ tidx,
                      const float* __restrict__ w1, const float* __restrict__ b1,
                      const float* __restrict__ w2, const float* __restrict__ b2,
                      float* __restrict__ agg) {
    __shared__ float xs[4][80];
    __shared__ float hs[4][64];
    int w = threadIdx.x >> 6, lane = threadIdx.x & 63;
    int e = blockIdx.x * 4 + w;                        // 6720 edges, 1680 blocks
    int from = fidx[e], to = tidx[e];
    if (lane < 32) xs[w][lane] = h[from * kD + lane];
    else           xs[w][lane] = h[to * kD + (lane - 32)];
    if (lane < 16) xs[w][64 + lane] = ee[e * 16 + lane];
    __syncthreads();
    float acc = b1[lane];
    #pragma unroll 8
    for (int k = 0; k < 80; ++k) acc += xs[w][k] * w1[k * 64 + lane];
    hs[w][lane] = fmaxf(acc, 0.f);
    __syncthreads();
    float o = b2[lane];
    #pragma unroll 8
    for (int k = 0; k < 64; ++k) o += hs[w][k] * w2[k * 64 + lane];
    atomicAdd(&agg[to * 64 + lane], o);
}

// ---------------- node update (also re-zeroes agg for next round) ----------------
__global__ void k_upd(float* __restrict__ h, float* __restrict__ agg,
                      const float* __restrict__ w1, const float* __restrict__ b1,
                      const float* __restrict__ w2, const float* __restrict__ b2) {
    __shared__ float xs[4][96];
    __shared__ float hs[4][64];
    int w = threadIdx.x >> 6, lane = threadIdx.x & 63;
    int n = blockIdx.x * 4 + w;                        // 1728 nodes, 432 blocks
    xs[w][lane] = agg[n * 64 + lane];
    agg[n * 64 + lane] = 0.f;                          // zero for next prop round
    if (lane < 32) xs[w][64 + lane] = h[n * kD + lane];
    __syncthreads();
    float acc = b1[lane];
    #pragma unroll 8
    for (int k = 0; k < 96; ++k) acc += xs[w][k] * w1[k * 64 + lane];
    hs[w][lane] = fmaxf(acc, 0.f);
    __syncthreads();
    if (lane < 32) {
        float o = b2[lane];
        #pragma unroll 8
        for (int k = 0; k < 64; ++k) o += hs[w][k] * w2[k * 32 + lane];
        h[n * kD + lane] += o;
    }
}

// ---------------- build Hq/Hc (padded) + sink MLP t-vectors ----------------
__global__ void k_sink_t(const float* __restrict__ h,
                         const float* __restrict__ w1, const float* __restrict__ b1,
                         const float* __restrict__ w2, const float* __restrict__ b2,
                         float* __restrict__ Hq, float* __restrict__ Hc,
                         float* __restrict__ tq, float* __restrict__ tc) {
    __shared__ float xs[4][32];
    __shared__ float hs[4][20];
    int w = threadIdx.x >> 6, lane = threadIdx.x & 63;
    int id = blockIdx.x * 4 + w;                       // 2*48*20 = 1920, 480 blocks
    int side = id / (kB * kNM);
    int rem  = id % (kB * kNM);
    int b = rem / kNM, i = rem % kNM;
    if (lane < 32) {
        float v;
        if (side == 0) v = h[(b * 36 + i) * kD + lane];
        else           v = (i < kNC) ? h[(b * 36 + kNQ + i) * kD + lane] : 0.f;
        (side ? Hc : Hq)[(b * kNM + i) * kD + lane] = v;
        xs[w][lane] = v;
    }
    __syncthreads();
    if (lane < kNM) {
        float acc = b1[lane];
        #pragma unroll
        for (int k = 0; k < kD; ++k) acc += xs[w][k] * w1[k * kNM + lane];
        hs[w][lane] = fmaxf(acc, 0.f);
    }
    __syncthreads();
    if (lane < kNM) {
        float o = b2[lane];
        #pragma unroll
        for (int k = 0; k < kNM; ++k) o += hs[w][k] * w2[k * kNM + lane];
        (side ? tc : tq)[(b * kNM + i) * kNM + lane] = o;
    }
}

// ---------------- cost + Sinkhorn + node_align ----------------
__global__ void k_sinkhorn(const float* __restrict__ tq, const float* __restrict__ tc,
                           const float* __restrict__ Hq,
                           float* __restrict__ P, float* __restrict__ out) {
    __shared__ float la[400], A[400], C[400];
    int b = blockIdx.x, t = threadIdx.x;               // 48 blocks x 64 threads
    for (int idx = t; idx < 400; idx += 64) { A[idx] = tq[b * 400 + idx]; C[idx] = tc[b * 400 + idx]; }
    __syncthreads();
    for (int pr = t; pr < 400; pr += 64) {
        int i = pr / 20, j = pr % 20;
        float c = 0.f;
        #pragma unroll
        for (int k = 0; k < 20; ++k) c += fabsf(A[i * 20 + k] - C[j * 20 + k]);
        la[pr] = -c * kInvT;
    }
    __syncthreads();
    for (int it = 0; it < kIters; ++it) {
        if (t < 20) {                                  // row LSE (over j)
            float m = -3.0e38f;
            #pragma unroll
            for (int j = 0; j < 20; ++j) m = fmaxf(m, la[t * 20 + j]);
            float s = 0.f;
            #pragma unroll
            for (int j = 0; j < 20; ++j) s += expf(la[t * 20 + j] - m);
            float l = m + logf(s);
            #pragma unroll
            for (int j = 0; j < 20; ++j) la[t * 20 + j] -= l;
        }
        __syncthreads();
        if (t < 20) {                                  // col LSE (over i)
            float m = -3.0e38f;
            #pragma unroll
            for (int i = 0; i < 20; ++i) m = fmaxf(m, la[i * 20 + t]);
            float s = 0.f;
            #pragma unroll
            for (int i = 0; i < 20; ++i) s += expf(la[i * 20 + t] - m);
            float l = m + logf(s);
            #pragma unroll
            for (int i = 0; i < 20; ++i) la[i * 20 + t] -= l;
        }
        __syncthreads();
    }
    for (int idx = t; idx < 400; idx += 64) P[b * 400 + idx] = expf(la[idx]);
    // node_align: NXOR nonzero only for j>=16 where Hc==0 -> ncost = L1(Hq row)
    float part = 0.f;
    if (t < 20) {
        float pr = 0.f;
        #pragma unroll
        for (int j = 16; j < 20; ++j) pr += expf(la[t * 20 + j]);
        float l1 = 0.f;
        #pragma unroll
        for (int k = 0; k < 32; ++k) l1 += fabsf(Hq[(b * 20 + t) * 32 + k]);
        part = pr * l1;
    }
    #pragma unroll
    for (int off = 32; off; off >>= 1) part += __shfl_down(part, off, 64);
    if (t == 0) atomicAdd(&out[b], part);
}

// ---------------- edge embeddings (f + bk fused, both sides) ----------------
__global__ void k_edge_emb(const float* __restrict__ Hq, const float* __restrict__ Hc,
                           const float* __restrict__ qadj, const float* __restrict__ cadj,
                           const float* __restrict__ w1, const float* __restrict__ b1,
                           const float* __restrict__ w2, const float* __restrict__ b2,
                           float* __restrict__ Eq, float* __restrict__ Ec) {
    __shared__ float xs[4][66];
    __shared__ float hs[4][64];
    int w = threadIdx.x >> 6, lane = threadIdx.x & 63;
    int id = blockIdx.x * 4 + w;                       // 2*48*190 = 18240, 4560 blocks
    int side = id / (kB * kNP);
    int rem  = id % (kB * kNP);
    int b = rem / kNP, p = rem % kNP;
    int sp, dp; pair_sd(p, sp, dp);
    const float* H   = side ? Hc : Hq;
    const float* adj = side ? cadj : qadj;
    if (lane < 32) xs[w][lane] = H[(b * kNM + sp) * kD + lane];
    else           xs[w][lane] = H[(b * kNM + dp) * kD + (lane - 32)];
    if (lane == 0) xs[w][64] = adj[b * 400 + sp * 20 + dp];
    __syncthreads();
    float af = b1[lane], ab = af;
    #pragma unroll 8
    for (int k = 0; k < 64; ++k) {
        float wk = w1[k * 64 + lane];
        af += xs[w][k] * wk;
        ab += xs[w][(k + 32) & 63] * wk;
    }
    {
        float wk = w1[64 * 64 + lane];
        float ev = xs[w][64];
        af += ev * wk; ab += ev * wk;
    }
    hs[w][lane] = fmaxf(af, 0.f) + fmaxf(ab, 0.f);
    __syncthreads();
    float o = 2.f * b2[lane];
    #pragma unroll 8
    for (int k = 0; k < 64; ++k) o += hs[w][k] * w2[k * 64 + lane];
    (side ? Ec : Eq)[(b * kNP + p) * 64 + lane] = o;
}

// ---------------- edge_align: lanes = feature dim, Ec tile in registers ----------
// grid: 48 b x 3 qtiles x 8 pchunks = 1152 blocks of 256 (4 waves)
__global__ void k_final(const float* __restrict__ P, const float* __restrict__ Eq,
                        const float* __restrict__ Ec, const float* __restrict__ qadj,
                        const float* __restrict__ cadj, float* __restrict__ out) {
    __shared__ float Ps[400];
    int bid = blockIdx.x;
    int b  = bid / 24;
    int r  = bid % 24;
    int qt = r / 8;          // 0..2  (q tile of 64)
    int pc = r % 8;          // 0..7  (p chunk)
    int t = threadIdx.x, w = t >> 6, lane = t & 63;
    for (int idx = t; idx < 400; idx += 256) Ps[idx] = P[b * 400 + idx];
    __syncthreads();

    int q0 = qt * 64;
    int q  = q0 + lane;
    bool qvalid = q < kNP;
    int sq = 0, dq = 0;
    if (qvalid) pair_sd(q, sq, dq);
    float acv = qvalid ? cadj[b * 400 + sq * 20 + dq] : 0.f;

    // Ec tile in registers: ec[j] = Ec[b, q0+j, lane]  (statically indexed)
    float ec[64];
    const float* ecb = Ec + (b * kNP + q0) * 64 + lane;
    #pragma unroll
    for (int j = 0; j < 64; ++j)
        ec[j] = (q0 + j < kNP) ? ecb[j * 64] : 0.f;

    float partial = 0.f;
    for (int i = 0; i < 6; ++i) {
        int p = pc * 4 + w + i * 32;
        if (p >= kNP) break;
        int sp, dp; pair_sd(p, sp, dp);
        float aq = qadj[b * 400 + sp * 20 + dp];
        float wqv = 0.f;
        if (qvalid) {
            float eT = Ps[sp * 20 + sq] * Ps[dp * 20 + dq]
                     + Ps[sp * 20 + dq] * Ps[dp * 20 + sq];
            float gate = (aq > 0.5f) ? (1.f - acv) : acv;   // aq XOR ac
            wqv = gate * eT;
        }
        float eqv = Eq[(b * kNP + p) * 64 + lane];
        #pragma unroll
        for (int j = 0; j < 64; ++j) {
            float wq = __shfl(wqv, j, 64);                  // weight for q = q0+j
            partial += wq * fabsf(eqv - ec[j]);
        }
    }
    #pragma unroll
    for (int off = 32; off; off >>= 1) partial += __shfl_down(partial, off, 64);
    if (lane == 0) atomicAdd(&out[b], partial);
}

extern "C" void kernel_launch(void* const* d_in, const int* in_sizes, int n_in,
                              void* d_out, int out_size, void* d_ws, size_t ws_size,
                              hipStream_t stream) {
    auto f = [&](int i) { return (const float*)d_in[i]; };
    const float* nf   = f(0);
    const float* ef   = f(1);
    const float* qadj = f(2);
    const float* cadj = f(3);
    const int* from_idx = (const int*)d_in[24];
    const int* to_idx   = (const int*)d_in[25];
    float* out = (float*)d_out;

    float* ws  = (float*)d_ws;
    float* h   = ws;                       // 55296
    float* ee  = h   + 55296;              // 107520
    float* agg = ee  + 107520;             // 110592
    float* Hq  = agg + 110592;             // 30720
    float* Hc  = Hq  + 30720;              // 30720
    float* tq  = Hc  + 30720;              // 19200
    float* tc  = tq  + 19200;              // 19200
    float* P   = tc  + 19200;              // 19200
    float* Eq  = P   + 19200;              // 583680
    float* Ec  = Eq  + 583680;             // 583680

    hipMemsetAsync(out, 0, kB * sizeof(float), stream);
    hipMemsetAsync(agg, 0, kNTOT * kEH * sizeof(float), stream);

    k_enc_node<<<216, 256, 0, stream>>>(nf, f(4), f(5), h);
    k_enc_edge<<<420, 256, 0, stream>>>(ef, f(6), f(7), ee);
    for (int it = 0; it < 5; ++it) {
        k_msg<<<1680, 256, 0, stream>>>(h, ee, from_idx, to_idx,
                                        f(8), f(9), f(10), f(11), agg);
        k_upd<<<432, 256, 0, stream>>>(h, agg, f(12), f(13), f(14), f(15));
    }
    k_sink_t<<<480, 256, 0, stream>>>(h, f(16), f(17), f(18), f(19), Hq, Hc, tq, tc);
    k_sinkhorn<<<48, 64, 0, stream>>>(tq, tc, Hq, P, out);
    k_edge_emb<<<4560, 256, 0, stream>>>(Hq, Hc, qadj, cadj,
                                         f(20), f(21), f(22), f(23), Eq, Ec);
    k_final<<<kB * 24, 256, 0, stream>>>(P, Eq, Ec, qadj, cadj, out);
}